// Round 11
// baseline (123.646 us; speedup 1.0000x reference)
//
#include <hip/hip_runtime.h>
#include <stdint.h>

// RandomSelfAttention: B=2, S=4096, S2=2048, NH=8, H=64, NKEYS=64
// q:(B,S2,NH,H) f32, k/v:(B,S,NH,H) f32, idx:(B,S2,NKEYS) int
// out z:(B,S2,NH,H) f32
//
// MODEL (linear fit r2/r4/r9, per CU-wave-slot): cyc = 1.61*lines + 280.
// 1.61 cyc/64B-line = random-gather L2 ceiling (~70% of streaming);
// 280 cyc/wave = fixed overhead (launch + idx/q latency + drain).
// r9 (fp16 gather) = 268 lines -> ~712 cyc -> ~38us main + ~11us cvt.
// THIS ROUND: 2 queries per wave -> waves halve, fixed-overhead total
// halves, lines total unchanged. r10 post-mortem: packed fp16 math
// (fdot2/pk_fma) REGRESSED 7us -> reverted to r9 scalar cvt+fma.
// fp8 is out: fp16 added 0.004 absmax, fp8 ~60x rel-err -> ~0.2 >> 0.036.
//
// Lessons pinned: r3 = never hard-cap regs to 64 (750MB scratch spill);
// r5/r6/r7 = compiler refuses >4-load register batches (don't fight it);
// r8 = 32KB LDS/block chokes occupancy (stay LDS-free);
// r10 = packed f16 math loses to scalar cvt+fma here.
// Watch WRITE_SIZE (8MB = clean) for spills on any edit.
// Block swizzle: blockIdx%16 = (b,n) combo -> per-XCD L2 set ~2MB (fp16).

#define BB 2
#define SS 4096
#define S2V 2048
#define NHV 8
#define HV 64
#define NKV 64

typedef _Float16 half_t;
typedef _Float16 half8 __attribute__((ext_vector_type(8)));

#define NE ((size_t)BB * SS * NHV * HV)   // 4,194,304 elements in k (and v)

// ---- prepass: k,v fp32 -> fp16 into workspace (coalesced stream) ----
__global__ __launch_bounds__(256)
void cvt_kernel(const float* __restrict__ k, const float* __restrict__ v,
                half_t* __restrict__ kh, half_t* __restrict__ vh) {
    const size_t base = ((size_t)blockIdx.x * 256 + threadIdx.x) * 8;
    const float* src; half_t* dst; size_t off;
    if (base < NE) { src = k; dst = kh; off = base; }
    else           { src = v; dst = vh; off = base - NE; }
    const float4 a = *(const float4*)(src + off);
    const float4 b = *(const float4*)(src + off + 4);
    half8 h = { (_Float16)a.x, (_Float16)a.y, (_Float16)a.z, (_Float16)a.w,
                (_Float16)b.x, (_Float16)b.y, (_Float16)b.z, (_Float16)b.w };
    *(half8*)(dst + off) = h;
}

// ---- main: fp16 gather, 2 queries/wave. Lane = (g=lane>>3, hc=lane&7) ----
__global__ __launch_bounds__(256, 4)
void rsa_fp16_kernel(const float* __restrict__ q, const half_t* __restrict__ kh,
                     const half_t* __restrict__ vh, const int* __restrict__ idx,
                     float* __restrict__ out) {
    const int lane = threadIdx.x & 63;
    const int w    = threadIdx.x >> 6;
    const int bi   = blockIdx.x;

    const int combo = bi & 15;
    const int b     = combo >> 3;
    const int n     = combo & 7;
    const int qi    = ((bi >> 4) << 3) + w * 2;   // this wave: qi, qi+1

    const int g  = lane >> 3;    // key group 0..7
    const int hc = lane & 7;     // h-chunk 0..7 (half8 = 16B granularity)

    const size_t bq0 = (size_t)b * S2V + qi;

    // q chunks for both units (prescaled by h^-0.5 = 1/8)
    float qf[2][8];
#pragma unroll
    for (int u = 0; u < 2; ++u) {
        const float* qrow = q + ((bq0 + u) * NHV + n) * HV;
        const float4 qa = *(const float4*)(qrow + hc * 8);
        const float4 qb = *(const float4*)(qrow + hc * 8 + 4);
        qf[u][0] = qa.x * 0.125f; qf[u][1] = qa.y * 0.125f;
        qf[u][2] = qa.z * 0.125f; qf[u][3] = qa.w * 0.125f;
        qf[u][4] = qb.x * 0.125f; qf[u][5] = qb.y * 0.125f;
        qf[u][6] = qb.z * 0.125f; qf[u][7] = qb.w * 0.125f;
    }

    int my_off[2];
#pragma unroll
    for (int u = 0; u < 2; ++u)
        my_off[u] = idx[(bq0 + u) * NKV + lane] * (NHV * HV);

    const half_t* kb = kh + ((size_t)b * SS * NHV + n) * HV;
    const half_t* vb = vh + ((size_t)b * SS * NHV + n) * HV;

    // ---- phase 1: scores, both units interleaved. it = keys it*8+g ----
    float sc[2][8];
#pragma unroll
    for (int it = 0; it < 8; ++it) {
#pragma unroll
        for (int u = 0; u < 2; ++u) {
            const int off = __shfl(my_off[u], it * 8 + g, 64);
            const half8 kk = *(const half8*)(kb + off + hc * 8);
            float d = 0.f;
#pragma unroll
            for (int j = 0; j < 8; ++j) d = fmaf((float)kk[j], qf[u][j], d);
            d += __shfl_xor(d, 1);
            d += __shfl_xor(d, 2);
            d += __shfl_xor(d, 4);
            sc[u][it] = d;   // dot of key it*8+g for unit u, replicated in group
        }
    }

    // ---- softmax over 64 keys, per unit ----
    float rs[2];
#pragma unroll
    for (int u = 0; u < 2; ++u) {
        float m = sc[u][0];
#pragma unroll
        for (int it = 1; it < 8; ++it) m = fmaxf(m, sc[u][it]);
        m = fmaxf(m, __shfl_xor(m, 8));
        m = fmaxf(m, __shfl_xor(m, 16));
        m = fmaxf(m, __shfl_xor(m, 32));
        float ssum = 0.f;
#pragma unroll
        for (int it = 0; it < 8; ++it) {
            sc[u][it] = __expf(sc[u][it] - m);
            ssum += sc[u][it];
        }
        ssum += __shfl_xor(ssum, 8);
        ssum += __shfl_xor(ssum, 16);
        ssum += __shfl_xor(ssum, 32);
        rs[u] = __frcp_rn(ssum);
    }

    // ---- phase 2: z accumulate, both units interleaved ----
    float za[2][8] = {{0.f,0.f,0.f,0.f,0.f,0.f,0.f,0.f},
                      {0.f,0.f,0.f,0.f,0.f,0.f,0.f,0.f}};
#pragma unroll
    for (int it = 0; it < 8; ++it) {
#pragma unroll
        for (int u = 0; u < 2; ++u) {
            const int off = __shfl(my_off[u], it * 8 + g, 64);
            const half8 vv = *(const half8*)(vb + off + hc * 8);
            const float p = sc[u][it];
#pragma unroll
            for (int j = 0; j < 8; ++j) za[u][j] = fmaf(p, (float)vv[j], za[u][j]);
        }
    }

    // ---- cross-group reduce + store, per unit ----
#pragma unroll
    for (int u = 0; u < 2; ++u) {
#pragma unroll
        for (int j = 0; j < 8; ++j) {
            za[u][j] += __shfl_xor(za[u][j], 8);
            za[u][j] += __shfl_xor(za[u][j], 16);
            za[u][j] += __shfl_xor(za[u][j], 32);
        }
        if (g == 0) {
            float* orow = out + ((bq0 + u) * NHV + n) * HV + hc * 8;
            float4 o1 = make_float4(za[u][0] * rs[u], za[u][1] * rs[u],
                                    za[u][2] * rs[u], za[u][3] * rs[u]);
            float4 o2 = make_float4(za[u][4] * rs[u], za[u][5] * rs[u],
                                    za[u][6] * rs[u], za[u][7] * rs[u]);
            *(float4*)(orow)     = o1;
            *(float4*)(orow + 4) = o2;
        }
    }
}

// ---- fallback (proven round-6 fp32 path) if ws too small ----
__global__ __launch_bounds__(256)
void rsa_fp32_kernel(const float* __restrict__ q, const float* __restrict__ k,
                     const float* __restrict__ v, const int* __restrict__ idx,
                     float* __restrict__ out) {
    const int lane = threadIdx.x & 63;
    const int w    = threadIdx.x >> 6;
    const int bi   = blockIdx.x;
    const int combo = bi & 15;
    const int b     = combo >> 3;
    const int n     = combo & 7;
    const int qi    = ((bi >> 4) << 2) + w;
    const int g  = lane >> 4;
    const int hc = lane & 15;
    const size_t bq = (size_t)b * S2V + qi;
    const float* qrow = q + (bq * NHV + n) * HV;
    const float4 qv = *(const float4*)(qrow + hc * 4);
    const float4 q4 = make_float4(qv.x * 0.125f, qv.y * 0.125f,
                                  qv.z * 0.125f, qv.w * 0.125f);
    const int my_off = idx[bq * NKV + lane] * (NHV * HV);
    const float* kb = k + ((size_t)b * SS * NHV + n) * HV;
    const float* vb = v + ((size_t)b * SS * NHV + n) * HV;
    float sc[16];
#pragma unroll
    for (int it = 0; it < 16; ++it) {
        const int off = __shfl(my_off, it * 4 + g, 64);
        const float4 k4 = *(const float4*)(kb + off + hc * 4);
        float d = k4.x * q4.x + k4.y * q4.y + k4.z * q4.z + k4.w * q4.w;
        d += __shfl_xor(d, 1);
        d += __shfl_xor(d, 2);
        d += __shfl_xor(d, 4);
        d += __shfl_xor(d, 8);
        sc[it] = d;
    }
    float m = sc[0];
#pragma unroll
    for (int it = 1; it < 16; ++it) m = fmaxf(m, sc[it]);
    m = fmaxf(m, __shfl_xor(m, 16));
    m = fmaxf(m, __shfl_xor(m, 32));
    float ssum = 0.f;
#pragma unroll
    for (int it = 0; it < 16; ++it) { sc[it] = __expf(sc[it] - m); ssum += sc[it]; }
    ssum += __shfl_xor(ssum, 16);
    ssum += __shfl_xor(ssum, 32);
    const float rs = __frcp_rn(ssum);
    float4 z = make_float4(0.f, 0.f, 0.f, 0.f);
#pragma unroll
    for (int it = 0; it < 16; ++it) {
        const int off = __shfl(my_off, it * 4 + g, 64);
        const float4 v4 = *(const float4*)(vb + off + hc * 4);
        const float p = sc[it];
        z.x = fmaf(p, v4.x, z.x); z.y = fmaf(p, v4.y, z.y);
        z.z = fmaf(p, v4.z, z.z); z.w = fmaf(p, v4.w, z.w);
    }
    z.x += __shfl_xor(z.x, 16); z.y += __shfl_xor(z.y, 16);
    z.z += __shfl_xor(z.z, 16); z.w += __shfl_xor(z.w, 16);
    z.x += __shfl_xor(z.x, 32); z.y += __shfl_xor(z.y, 32);
    z.z += __shfl_xor(z.z, 32); z.w += __shfl_xor(z.w, 32);
    if (g == 0) {
        float4 zo = make_float4(z.x * rs, z.y * rs, z.z * rs, z.w * rs);
        *(float4*)(out + (bq * NHV + n) * HV + hc * 4) = zo;
    }
}

extern "C" void kernel_launch(void* const* d_in, const int* in_sizes, int n_in,
                              void* d_out, int out_size, void* d_ws, size_t ws_size,
                              hipStream_t stream) {
    const float* q   = (const float*)d_in[0];
    const float* k   = (const float*)d_in[1];
    const float* v   = (const float*)d_in[2];
    const int*   idx = (const int*)d_in[3];
    float*       out = (float*)d_out;

    const size_t need = 2 * NE * sizeof(half_t);   // 16.8 MB
    if (ws_size >= need) {
        half_t* kh = (half_t*)d_ws;
        half_t* vh = kh + NE;
        const int cvt_blocks = (int)(2 * NE / 8 / 256);   // 4096
        cvt_kernel<<<cvt_blocks, 256, 0, stream>>>(k, v, kh, vh);
        // 32768 units / 2 per wave / 4 waves per block = 4096 blocks
        rsa_fp16_kernel<<<4096, 256, 0, stream>>>(q, kh, vh, idx, out);
    } else {
        const int blocks = BB * S2V * NHV / 4;         // 8192
        rsa_fp32_kernel<<<blocks, 256, 0, stream>>>(q, k, v, idx, out);
    }
}

// Round 12
// 115.358 us; speedup vs baseline: 1.0718x; 1.0718x over previous
//
#include <hip/hip_runtime.h>
#include <stdint.h>

// RandomSelfAttention: B=2, S=4096, S2=2048, NH=8, H=64, NKEYS=64
// q:(B,S2,NH,H) f32, k/v:(B,S,NH,H) f32, idx:(B,S2,NKEYS) int
// out z:(B,S2,NH,H) f32
//
// MODEL (refit r2/r4/r9/r11, per-CU cycles): dur = VALU_issue + lines/0.7,
// ADDITIVE (poor mem/VALU overlap; 5 structural attacks failed to fuse
// them: r5/r6 reg batches, r7 tier pin, r8 LDS-DMA, r11 2q/wave).
// r9 best: fp16 gather (268 line-transactions/wave), scalar mix-fma math,
// 1 unit/wave. This round: r9 + 1024-thread blocks (2048 blocks, 4x fewer
// dispatch events) to shave the CP ramp/drain visible as ~29% avg occupancy.
//
// Lessons pinned: r3 = never hard-cap regs to 64 (750MB scratch spill);
// r5/r6/r7 = compiler refuses >4-load register batches / pins to 64-VGPR
// tier (don't fight it); r8 = 32KB LDS/block chokes occupancy (LDS-free);
// r10 = packed fdot2/pk_fma regressed +7us; r11 = 2 units/wave regressed
// (arrays inside 64-VGPR tier kill ILP). Watch WRITE_SIZE (8MB = clean).
// Block swizzle: blockIdx%16 = (b,n) combo -> per-XCD L2 set ~2MB (fp16).

#define BB 2
#define SS 4096
#define S2V 2048
#define NHV 8
#define HV 64
#define NKV 64

typedef _Float16 half_t;
typedef _Float16 half8 __attribute__((ext_vector_type(8)));

#define NE ((size_t)BB * SS * NHV * HV)   // 4,194,304 elements in k (and v)

// ---- prepass: k,v fp32 -> fp16 into workspace (coalesced stream) ----
__global__ __launch_bounds__(1024)
void cvt_kernel(const float* __restrict__ k, const float* __restrict__ v,
                half_t* __restrict__ kh, half_t* __restrict__ vh) {
    const size_t base = ((size_t)blockIdx.x * 1024 + threadIdx.x) * 8;
    const float* src; half_t* dst; size_t off;
    if (base < NE) { src = k; dst = kh; off = base; }
    else           { src = v; dst = vh; off = base - NE; }
    const float4 a = *(const float4*)(src + off);
    const float4 b = *(const float4*)(src + off + 4);
    half8 h = { (_Float16)a.x, (_Float16)a.y, (_Float16)a.z, (_Float16)a.w,
                (_Float16)b.x, (_Float16)b.y, (_Float16)b.z, (_Float16)b.w };
    *(half8*)(dst + off) = h;
}

// ---- main: fp16 gather, 1 query/wave. Lane = (g=lane>>3, hc=lane&7) ----
__global__ __launch_bounds__(1024)
void rsa_fp16_kernel(const float* __restrict__ q, const half_t* __restrict__ kh,
                     const half_t* __restrict__ vh, const int* __restrict__ idx,
                     float* __restrict__ out) {
    const int lane = threadIdx.x & 63;
    const int w    = threadIdx.x >> 6;      // wave 0..15 in block
    const int bi   = blockIdx.x;

    const int combo = bi & 15;
    const int b     = combo >> 3;
    const int n     = combo & 7;
    const int qi    = ((bi >> 4) << 4) + w; // 16 queries per block

    const int g  = lane >> 3;    // key group 0..7
    const int hc = lane & 7;     // h-chunk 0..7 (half8 = 16B granularity)

    const size_t bq = (size_t)b * S2V + qi;

    // q chunk: 8 floats (prescaled by h^-0.5 = 1/8)
    const float* qrow = q + (bq * NHV + n) * HV;
    const float4 qa = *(const float4*)(qrow + hc * 8);
    const float4 qb = *(const float4*)(qrow + hc * 8 + 4);
    float qf[8] = { qa.x * 0.125f, qa.y * 0.125f, qa.z * 0.125f, qa.w * 0.125f,
                    qb.x * 0.125f, qb.y * 0.125f, qb.z * 0.125f, qb.w * 0.125f };

    const int my_off = idx[bq * NKV + lane] * (NHV * HV);

    const half_t* kb = kh + ((size_t)b * SS * NHV + n) * HV;
    const half_t* vb = vh + ((size_t)b * SS * NHV + n) * HV;

    // ---- phase 1: scores. iter it covers keys it*8 + g (8 rows/instr) ----
    float sc[8];
#pragma unroll
    for (int it = 0; it < 8; ++it) {
        const int off = __shfl(my_off, it * 8 + g, 64);
        const half8 kk = *(const half8*)(kb + off + hc * 8);
        float d = 0.f;
#pragma unroll
        for (int j = 0; j < 8; ++j) d = fmaf((float)kk[j], qf[j], d);
        d += __shfl_xor(d, 1);
        d += __shfl_xor(d, 2);
        d += __shfl_xor(d, 4);
        sc[it] = d;   // full dot of key it*8+g, replicated over 8-lane group
    }

    // ---- softmax over 64 keys ----
    float m = sc[0];
#pragma unroll
    for (int it = 1; it < 8; ++it) m = fmaxf(m, sc[it]);
    m = fmaxf(m, __shfl_xor(m, 8));
    m = fmaxf(m, __shfl_xor(m, 16));
    m = fmaxf(m, __shfl_xor(m, 32));

    float ssum = 0.f;
#pragma unroll
    for (int it = 0; it < 8; ++it) {
        sc[it] = __expf(sc[it] - m);
        ssum += sc[it];
    }
    ssum += __shfl_xor(ssum, 8);
    ssum += __shfl_xor(ssum, 16);
    ssum += __shfl_xor(ssum, 32);
    const float rs = __frcp_rn(ssum);

    // ---- phase 2: z = sum_key p[key] * v_row[key] ----
    float za[8] = {0.f, 0.f, 0.f, 0.f, 0.f, 0.f, 0.f, 0.f};
#pragma unroll
    for (int it = 0; it < 8; ++it) {
        const int off = __shfl(my_off, it * 8 + g, 64);
        const half8 vv = *(const half8*)(vb + off + hc * 8);
        const float p = sc[it];
#pragma unroll
        for (int j = 0; j < 8; ++j) za[j] = fmaf(p, (float)vv[j], za[j]);
    }
    // reduce partial z across the 8 key groups
#pragma unroll
    for (int j = 0; j < 8; ++j) {
        za[j] += __shfl_xor(za[j], 8);
        za[j] += __shfl_xor(za[j], 16);
        za[j] += __shfl_xor(za[j], 32);
    }

    if (g == 0) {
        float* orow = out + (bq * NHV + n) * HV + hc * 8;
        float4 o1 = make_float4(za[0] * rs, za[1] * rs, za[2] * rs, za[3] * rs);
        float4 o2 = make_float4(za[4] * rs, za[5] * rs, za[6] * rs, za[7] * rs);
        *(float4*)(orow)     = o1;
        *(float4*)(orow + 4) = o2;
    }
}

// ---- fallback (proven round-6 fp32 path) if ws too small ----
__global__ __launch_bounds__(256)
void rsa_fp32_kernel(const float* __restrict__ q, const float* __restrict__ k,
                     const float* __restrict__ v, const int* __restrict__ idx,
                     float* __restrict__ out) {
    const int lane = threadIdx.x & 63;
    const int w    = threadIdx.x >> 6;
    const int bi   = blockIdx.x;
    const int combo = bi & 15;
    const int b     = combo >> 3;
    const int n     = combo & 7;
    const int qi    = ((bi >> 4) << 2) + w;
    const int g  = lane >> 4;
    const int hc = lane & 15;
    const size_t bq = (size_t)b * S2V + qi;
    const float* qrow = q + (bq * NHV + n) * HV;
    const float4 qv = *(const float4*)(qrow + hc * 4);
    const float4 q4 = make_float4(qv.x * 0.125f, qv.y * 0.125f,
                                  qv.z * 0.125f, qv.w * 0.125f);
    const int my_off = idx[bq * NKV + lane] * (NHV * HV);
    const float* kb = k + ((size_t)b * SS * NHV + n) * HV;
    const float* vb = v + ((size_t)b * SS * NHV + n) * HV;
    float sc[16];
#pragma unroll
    for (int it = 0; it < 16; ++it) {
        const int off = __shfl(my_off, it * 4 + g, 64);
        const float4 k4 = *(const float4*)(kb + off + hc * 4);
        float d = k4.x * q4.x + k4.y * q4.y + k4.z * q4.z + k4.w * q4.w;
        d += __shfl_xor(d, 1);
        d += __shfl_xor(d, 2);
        d += __shfl_xor(d, 4);
        d += __shfl_xor(d, 8);
        sc[it] = d;
    }
    float m = sc[0];
#pragma unroll
    for (int it = 1; it < 16; ++it) m = fmaxf(m, sc[it]);
    m = fmaxf(m, __shfl_xor(m, 16));
    m = fmaxf(m, __shfl_xor(m, 32));
    float ssum = 0.f;
#pragma unroll
    for (int it = 0; it < 16; ++it) { sc[it] = __expf(sc[it] - m); ssum += sc[it]; }
    ssum += __shfl_xor(ssum, 16);
    ssum += __shfl_xor(ssum, 32);
    const float rs = __frcp_rn(ssum);
    float4 z = make_float4(0.f, 0.f, 0.f, 0.f);
#pragma unroll
    for (int it = 0; it < 16; ++it) {
        const int off = __shfl(my_off, it * 4 + g, 64);
        const float4 v4 = *(const float4*)(vb + off + hc * 4);
        const float p = sc[it];
        z.x = fmaf(p, v4.x, z.x); z.y = fmaf(p, v4.y, z.y);
        z.z = fmaf(p, v4.z, z.z); z.w = fmaf(p, v4.w, z.w);
    }
    z.x += __shfl_xor(z.x, 16); z.y += __shfl_xor(z.y, 16);
    z.z += __shfl_xor(z.z, 16); z.w += __shfl_xor(z.w, 16);
    z.x += __shfl_xor(z.x, 32); z.y += __shfl_xor(z.y, 32);
    z.z += __shfl_xor(z.z, 32); z.w += __shfl_xor(z.w, 32);
    if (g == 0) {
        float4 zo = make_float4(z.x * rs, z.y * rs, z.z * rs, z.w * rs);
        *(float4*)(out + (bq * NHV + n) * HV + hc * 4) = zo;
    }
}

extern "C" void kernel_launch(void* const* d_in, const int* in_sizes, int n_in,
                              void* d_out, int out_size, void* d_ws, size_t ws_size,
                              hipStream_t stream) {
    const float* q   = (const float*)d_in[0];
    const float* k   = (const float*)d_in[1];
    const float* v   = (const float*)d_in[2];
    const int*   idx = (const int*)d_in[3];
    float*       out = (float*)d_out;

    const size_t need = 2 * NE * sizeof(half_t);   // 16.8 MB
    if (ws_size >= need) {
        half_t* kh = (half_t*)d_ws;
        half_t* vh = kh + NE;
        const int cvt_blocks = (int)(2 * NE / 8 / 1024);   // 1024
        cvt_kernel<<<cvt_blocks, 1024, 0, stream>>>(k, v, kh, vh);
        // 32768 units / 16 per block = 2048 blocks
        rsa_fp16_kernel<<<2048, 1024, 0, stream>>>(q, kh, vh, idx, out);
    } else {
        const int blocks = BB * S2V * NHV / 4;             // 8192
        rsa_fp32_kernel<<<blocks, 256, 0, stream>>>(q, k, v, idx, out);
    }
}

// Round 13
// 113.393 us; speedup vs baseline: 1.0904x; 1.0173x over previous
//
#include <hip/hip_runtime.h>
#include <stdint.h>

// RandomSelfAttention: B=2, S=4096, S2=2048, NH=8, H=64, NKEYS=64
// q:(B,S2,NH,H) f32, k/v:(B,S,NH,H) f32, idx:(B,S2,NKEYS) int
// out z:(B,S2,NH,H) f32
//
// MODEL (refit r2-r12, per-CU cycles, ADDITIVE): dur = VALU_issue(~42K) +
// lines/0.7 (~48K). Six structural overlap attempts failed (r5/r6 reg
// batches, r7 tier pin, r8 LDS-DMA, r11 2q/wave, r12 big blocks).
// Gather-line term is compulsory (fp16 slices = 2 lines/row, each line
// touched once). Remaining lever = VALU issue count.
// THIS ROUND (single variable vs r9 baseline): fdot2 in phase 1 only
// (4 v_dot2_f32_f16 replace 8 cvt + 8 fma per it), offs[8] reused across
// phases. Phase 2 stays r9-scalar (8 independent f32 chains — r10 showed
// pk_fma f16 accumulation there regresses).
//
// Lessons pinned: r3 = never hard-cap regs to 64 (750MB scratch spill);
// r5/r6/r7 = compiler pins to 64-VGPR tier, refuses big load batches;
// r8 = 32KB LDS/block chokes occupancy; r10 = pk_fma f16-accum phase 2
// regressed; r11 = 2 units/wave regressed; r12 = 1024-thr blocks neutral.
// Watch WRITE_SIZE (8MB = clean) for spills on any edit.
// Block swizzle: blockIdx%16 = (b,n) combo -> per-XCD L2 set ~2MB (fp16).

#define BB 2
#define SS 4096
#define S2V 2048
#define NHV 8
#define HV 64
#define NKV 64

typedef _Float16 half_t;
typedef _Float16 half8 __attribute__((ext_vector_type(8)));
typedef _Float16 half2t __attribute__((ext_vector_type(2)));

#define NE ((size_t)BB * SS * NHV * HV)   // 4,194,304 elements in k (and v)

// ---- prepass: k,v fp32 -> fp16 into workspace (coalesced stream) ----
__global__ __launch_bounds__(256)
void cvt_kernel(const float* __restrict__ k, const float* __restrict__ v,
                half_t* __restrict__ kh, half_t* __restrict__ vh) {
    const size_t base = ((size_t)blockIdx.x * 256 + threadIdx.x) * 8;
    const float* src; half_t* dst; size_t off;
    if (base < NE) { src = k; dst = kh; off = base; }
    else           { src = v; dst = vh; off = base - NE; }
    const float4 a = *(const float4*)(src + off);
    const float4 b = *(const float4*)(src + off + 4);
    half8 h = { (_Float16)a.x, (_Float16)a.y, (_Float16)a.z, (_Float16)a.w,
                (_Float16)b.x, (_Float16)b.y, (_Float16)b.z, (_Float16)b.w };
    *(half8*)(dst + off) = h;
}

// ---- main: fp16 gather, 1 query/wave. Lane = (g=lane>>3, hc=lane&7) ----
__global__ __launch_bounds__(256)
void rsa_fp16_kernel(const float* __restrict__ q, const half_t* __restrict__ kh,
                     const half_t* __restrict__ vh, const int* __restrict__ idx,
                     float* __restrict__ out) {
    const int lane = threadIdx.x & 63;
    const int w    = threadIdx.x >> 6;
    const int bi   = blockIdx.x;

    const int combo = bi & 15;
    const int b     = combo >> 3;
    const int n     = combo & 7;
    const int qi    = ((bi >> 4) << 2) + w;

    const int g  = lane >> 3;    // key group 0..7
    const int hc = lane & 7;     // h-chunk 0..7 (half8 = 16B granularity)

    const size_t bq = (size_t)b * S2V + qi;

    // q chunk: 8 floats, prescaled by h^-0.5 = 1/8, converted to half8 once
    const float* qrow = q + (bq * NHV + n) * HV;
    const float4 qa = *(const float4*)(qrow + hc * 8);
    const float4 qb = *(const float4*)(qrow + hc * 8 + 4);
    const half8 qh = { (_Float16)(qa.x * 0.125f), (_Float16)(qa.y * 0.125f),
                       (_Float16)(qa.z * 0.125f), (_Float16)(qa.w * 0.125f),
                       (_Float16)(qb.x * 0.125f), (_Float16)(qb.y * 0.125f),
                       (_Float16)(qb.z * 0.125f), (_Float16)(qb.w * 0.125f) };
    const half2t* q2 = (const half2t*)&qh;

    const int my_off = idx[bq * NKV + lane] * (NHV * HV);

    const half_t* kb = kh + ((size_t)b * SS * NHV + n) * HV;
    const half_t* vb = vh + ((size_t)b * SS * NHV + n) * HV;

    // ---- phase 1: scores via fdot2. iter it covers keys it*8 + g ----
    int   offs[8];
    float sc[8];
#pragma unroll
    for (int it = 0; it < 8; ++it) {
        const int off = __shfl(my_off, it * 8 + g, 64);
        offs[it] = off;
        const half8 kk = *(const half8*)(kb + off + hc * 8);
        float d = 0.f;
#if __has_builtin(__builtin_amdgcn_fdot2)
        const half2t* k2 = (const half2t*)&kk;
#pragma unroll
        for (int j = 0; j < 4; ++j)
            d = __builtin_amdgcn_fdot2(k2[j], q2[j], d, false);
#else
#pragma unroll
        for (int j = 0; j < 8; ++j) d = fmaf((float)kk[j], (float)qh[j], d);
#endif
        d += __shfl_xor(d, 1);
        d += __shfl_xor(d, 2);
        d += __shfl_xor(d, 4);
        sc[it] = d;   // full dot of key it*8+g, replicated over 8-lane group
    }

    // ---- softmax over 64 keys ----
    float m = sc[0];
#pragma unroll
    for (int it = 1; it < 8; ++it) m = fmaxf(m, sc[it]);
    m = fmaxf(m, __shfl_xor(m, 8));
    m = fmaxf(m, __shfl_xor(m, 16));
    m = fmaxf(m, __shfl_xor(m, 32));

    float ssum = 0.f;
#pragma unroll
    for (int it = 0; it < 8; ++it) {
        sc[it] = __expf(sc[it] - m);
        ssum += sc[it];
    }
    ssum += __shfl_xor(ssum, 8);
    ssum += __shfl_xor(ssum, 16);
    ssum += __shfl_xor(ssum, 32);
    const float rs = __frcp_rn(ssum);

    // ---- phase 2: z = sum_key p[key] * v_row[key] (scalar f32, 8 chains) ----
    float za[8] = {0.f, 0.f, 0.f, 0.f, 0.f, 0.f, 0.f, 0.f};
#pragma unroll
    for (int it = 0; it < 8; ++it) {
        const half8 vv = *(const half8*)(vb + offs[it] + hc * 8);
        const float p = sc[it];
#pragma unroll
        for (int j = 0; j < 8; ++j) za[j] = fmaf(p, (float)vv[j], za[j]);
    }
    // reduce partial z across the 8 key groups
#pragma unroll
    for (int j = 0; j < 8; ++j) {
        za[j] += __shfl_xor(za[j], 8);
        za[j] += __shfl_xor(za[j], 16);
        za[j] += __shfl_xor(za[j], 32);
    }

    if (g == 0) {
        float* orow = out + (bq * NHV + n) * HV + hc * 8;
        float4 o1 = make_float4(za[0] * rs, za[1] * rs, za[2] * rs, za[3] * rs);
        float4 o2 = make_float4(za[4] * rs, za[5] * rs, za[6] * rs, za[7] * rs);
        *(float4*)(orow)     = o1;
        *(float4*)(orow + 4) = o2;
    }
}

// ---- fallback (proven round-6 fp32 path) if ws too small ----
__global__ __launch_bounds__(256)
void rsa_fp32_kernel(const float* __restrict__ q, const float* __restrict__ k,
                     const float* __restrict__ v, const int* __restrict__ idx,
                     float* __restrict__ out) {
    const int lane = threadIdx.x & 63;
    const int w    = threadIdx.x >> 6;
    const int bi   = blockIdx.x;
    const int combo = bi & 15;
    const int b     = combo >> 3;
    const int n     = combo & 7;
    const int qi    = ((bi >> 4) << 2) + w;
    const int g  = lane >> 4;
    const int hc = lane & 15;
    const size_t bq = (size_t)b * S2V + qi;
    const float* qrow = q + (bq * NHV + n) * HV;
    const float4 qv = *(const float4*)(qrow + hc * 4);
    const float4 q4 = make_float4(qv.x * 0.125f, qv.y * 0.125f,
                                  qv.z * 0.125f, qv.w * 0.125f);
    const int my_off = idx[bq * NKV + lane] * (NHV * HV);
    const float* kb = k + ((size_t)b * SS * NHV + n) * HV;
    const float* vb = v + ((size_t)b * SS * NHV + n) * HV;
    float sc[16];
#pragma unroll
    for (int it = 0; it < 16; ++it) {
        const int off = __shfl(my_off, it * 4 + g, 64);
        const float4 k4 = *(const float4*)(kb + off + hc * 4);
        float d = k4.x * q4.x + k4.y * q4.y + k4.z * q4.z + k4.w * q4.w;
        d += __shfl_xor(d, 1);
        d += __shfl_xor(d, 2);
        d += __shfl_xor(d, 4);
        d += __shfl_xor(d, 8);
        sc[it] = d;
    }
    float m = sc[0];
#pragma unroll
    for (int it = 1; it < 16; ++it) m = fmaxf(m, sc[it]);
    m = fmaxf(m, __shfl_xor(m, 16));
    m = fmaxf(m, __shfl_xor(m, 32));
    float ssum = 0.f;
#pragma unroll
    for (int it = 0; it < 16; ++it) { sc[it] = __expf(sc[it] - m); ssum += sc[it]; }
    ssum += __shfl_xor(ssum, 16);
    ssum += __shfl_xor(ssum, 32);
    const float rs = __frcp_rn(ssum);
    float4 z = make_float4(0.f, 0.f, 0.f, 0.f);
#pragma unroll
    for (int it = 0; it < 16; ++it) {
        const int off = __shfl(my_off, it * 4 + g, 64);
        const float4 v4 = *(const float4*)(vb + off + hc * 4);
        const float p = sc[it];
        z.x = fmaf(p, v4.x, z.x); z.y = fmaf(p, v4.y, z.y);
        z.z = fmaf(p, v4.z, z.z); z.w = fmaf(p, v4.w, z.w);
    }
    z.x += __shfl_xor(z.x, 16); z.y += __shfl_xor(z.y, 16);
    z.z += __shfl_xor(z.z, 16); z.w += __shfl_xor(z.w, 16);
    z.x += __shfl_xor(z.x, 32); z.y += __shfl_xor(z.y, 32);
    z.z += __shfl_xor(z.z, 32); z.w += __shfl_xor(z.w, 32);
    if (g == 0) {
        float4 zo = make_float4(z.x * rs, z.y * rs, z.z * rs, z.w * rs);
        *(float4*)(out + (bq * NHV + n) * HV + hc * 4) = zo;
    }
}

extern "C" void kernel_launch(void* const* d_in, const int* in_sizes, int n_in,
                              void* d_out, int out_size, void* d_ws, size_t ws_size,
                              hipStream_t stream) {
    const float* q   = (const float*)d_in[0];
    const float* k   = (const float*)d_in[1];
    const float* v   = (const float*)d_in[2];
    const int*   idx = (const int*)d_in[3];
    float*       out = (float*)d_out;

    const size_t need = 2 * NE * sizeof(half_t);   // 16.8 MB
    if (ws_size >= need) {
        half_t* kh = (half_t*)d_ws;
        half_t* vh = kh + NE;
        const int cvt_blocks = (int)(2 * NE / 8 / 256);   // 4096
        cvt_kernel<<<cvt_blocks, 256, 0, stream>>>(k, v, kh, vh);
        // 32768 units / 4 waves per block = 8192 blocks
        rsa_fp16_kernel<<<8192, 256, 0, stream>>>(q, kh, vh, idx, out);
    } else {
        const int blocks = BB * S2V * NHV / 4;             // 8192
        rsa_fp32_kernel<<<blocks, 256, 0, stream>>>(q, k, v, idx, out);
    }
}